// Round 10
// baseline (111.580 us; speedup 1.0000x reference)
//
#include <hip/hip_runtime.h>
#include <hip/hip_fp16.h>

#define HH 512
#define WD 512
#define HP 514
#define BN 8
#define CN 3

#define TH 16
#define TW 32

typedef float v2f __attribute__((ext_vector_type(2)));

// LDS tiles. sp4 is channel-packed float4 (.xyz = ch0..2) so one tap = one
// 16B-aligned ds_read_b128. sr/swm scalar with odd pitch (conflict-free).
// w9: per-WM-pixel fp16 cache of phase 2's 9 Gaussian weights (20 B/px,
// 5-dword stride -> 2-way bank aliasing = free), so phase 3 is just
// argmin/argmax + one dynamic u16 read.
#define SP_ROWS (TH + 6)          // 22  img_p rows [h0-2, h0+20)
#define SP_COLS (TW + 6)          // 38
#define SR_ROWS (TH + 4)          // 20  img_r rows [h0-2, h0+18)
#define SR_COLS (TW + 4)          // 36
#define SR_PITCH (SR_COLS + 1)    // 37
#define WM_ROWS (TH + 2)          // 18  w_mod rows [h0-1, h0+17)
#define WM_COLS (TW + 2)          // 34
#define WM_PITCH (WM_COLS + 1)    // 35
#define W9_STRIDE 10              // halves per pixel (9 used, 1 pad -> 20 B)

#define LOG2E 1.44269504088896340736f

// Robust per-batch flag read: contract says int32, hedge for bool bytes.
__device__ __forceinline__ int load_flag(const int* __restrict__ p, int b) {
    bool all01 = true;
#pragma unroll
    for (int i = 0; i < BN; ++i) {
        int v = p[i];
        all01 = all01 && (v == 0 || v == 1);
    }
    if (all01) return p[b];
    const unsigned char* pb = (const unsigned char*)p;
    return pb[b] != 0;
}

__device__ __forceinline__ float fast_rcp(float x) {
    return __builtin_amdgcn_rcpf(x);
}

__global__ __launch_bounds__(256) void fused(const float* __restrict__ img,
                                             const float* __restrict__ noise,
                                             const int* __restrict__ ids_sel,
                                             const int* __restrict__ ids_dil,
                                             int* __restrict__ out) {
    int b = blockIdx.z;
    int h0 = blockIdx.y * TH, w0 = blockIdx.x * TW;
    int t = threadIdx.x;

    if (!load_flag(ids_sel, b)) {  // uniform per block: plain uint8 copy
#pragma unroll
        for (int c = 0; c < CN; ++c) {
            const float* im = img + (size_t)(b * CN + c) * HH * WD;
            int* op = out + (size_t)(b * CN + c) * HH * WD;
#pragma unroll
            for (int rr = 0; rr < (TH * TW) / 256; ++rr) {
                int idx = rr * 256 + t;
                int r = idx / TW, cc = idx - r * TW;
                op[(h0 + r) * WD + w0 + cc] = ((int)im[(h0 + r) * WD + w0 + cc]) & 255;
            }
        }
        return;
    }
    bool dil = load_flag(ids_dil, b) != 0;

    __shared__ float4 sp4[SP_ROWS * SP_COLS];               // 13,376 B
    __shared__ float sr[SR_ROWS * SR_PITCH];                //  2,960 B
    __shared__ float swm[WM_ROWS * WM_PITCH];               //  2,520 B
    __shared__ __align__(4) __half w9[WM_ROWS * WM_COLS * W9_STRIDE];  // 12,240 B

    // Phase 1: stage img_p (3ch packed) rows [h0-2,h0+20), cols [w0-2,w0+36).
    // Index-clamped; clamped entries feed only out-of-image pixels (forced 0).
    {
        const float* nz = noise + (size_t)b * CN * HP * HP;
        const float* im = img + (size_t)b * CN * HH * WD;
        for (int idx = t; idx < SP_ROWS * SP_COLS; idx += 256) {
            int r = idx / SP_COLS, cc = idx - r * SP_COLS;
            int ip = h0 - 2 + r, jp = w0 - 2 + cc;
            ip = ip < 0 ? 0 : (ip > HP - 1 ? HP - 1 : ip);
            jp = jp < 0 ? 0 : (jp > HP - 1 ? HP - 1 : jp);
            bool in = (ip >= 1 && ip <= HH && jp >= 1 && jp <= WD);
            int no = ip * HP + jp;
            int io = (ip - 1) * WD + (jp - 1);
            float4 v;
            v.x = nz[no] + (in ? im[io] : 0.f);
            v.y = nz[HP * HP + no] + (in ? im[HH * WD + io] : 0.f);
            v.z = nz[2 * HP * HP + no] + (in ? im[2 * HH * WD + io] : 0.f);
            v.w = 0.f;
            sp4[idx] = v;
        }
    }
    __syncthreads();

    // Phase 2: img_r for pixel rows [h0-2,h0+18), cols [w0-2,w0+34), AND the
    // 9 per-pixel weights cached to w9 (fp16) for the WM sub-rect.
    // Restructured: ch0/1 packed as v2f (v_pk_* ops), d^2 computed once into
    // static-indexed register arrays, log2e folded into iv so the weight is a
    // bare v_exp_f32. min_c exp(-t_c) == exp(-max_c t_c).
    for (int idx = t; idx < SR_ROWS * SR_COLS; idx += 256) {
        int r = idx / SR_COLS, cc = idx - r * SR_COLS;
        int h = h0 - 2 + r, w = w0 - 2 + cc;
        float val = 0.f;
        if (h >= 0 && h < HH && w >= 0 && w < WD) {
            v2f vxy[9];
            float vz[9];
            v2f sxy = {0.f, 0.f};
            float sz = 0.f;
#pragma unroll
            for (int k = 0; k < 9; ++k) {
                float4 tp = sp4[(r + k / 3) * SP_COLS + cc + k % 3];
                vxy[k] = (v2f){tp.x, tp.y};
                vz[k] = tp.z;
                sxy += vxy[k];
                sz += tp.z;
            }
            v2f mxy = sxy * (1.f / 9.f);
            float mz = sz * (1.f / 9.f);
            v2f d2xy[9];
            float d2z[9], s3[9];
            v2f sdxy = {0.f, 0.f};
            float sdz = 0.f;
#pragma unroll
            for (int k = 0; k < 9; ++k) {
                v2f dxy = vxy[k] - mxy;
                float dz = vz[k] - mz;
                d2xy[k] = dxy * dxy;
                d2z[k] = dz * dz;
                sdxy += d2xy[k];
                sdz += d2z[k];
                s3[k] = vxy[k].x + vxy[k].y + vz[k];
            }
            // iv = log2e / (2*var) with var = sd/8 (ddof=1): 4*log2e/sd.
            // log2e > 0 commutes with max, so exp2 of the max is exact algebra.
            v2f ivxy;
            ivxy.x = (4.f * LOG2E) * fast_rcp(sdxy.x);
            ivxy.y = (4.f * LOG2E) * fast_rcp(sdxy.y);
            float ivz = (4.f * LOG2E) * fast_rcp(sdz);
            float wk[9];
            float num = 0.f, den = 0.f;
#pragma unroll
            for (int k = 0; k < 9; ++k) {
                v2f txy = d2xy[k] * ivxy;           // v_pk_mul_f32
                float m = fmaxf(fmaxf(txy.x, txy.y), d2z[k] * ivz);
                wk[k] = __builtin_amdgcn_exp2f(-m);  // bare v_exp_f32
                num += s3[k] * wk[k];
                den += wk[k];
            }
            val = num * fast_rcp(den);
            // cache the 9 weights (fp16, packed dword writes) for phase 3
            if (r >= 1 && r < SR_ROWS - 1 && cc >= 1 && cc < SR_COLS - 1) {
                int pix = (r - 1) * WM_COLS + (cc - 1);
                unsigned int* wp = (unsigned int*)&w9[pix * W9_STRIDE];
#pragma unroll
                for (int k = 0; k < 4; ++k) {
                    __half2 h2 = __floats2half2_rn(wk[2 * k], wk[2 * k + 1]);
                    wp[k] = *(unsigned int*)&h2;
                }
                w9[pix * W9_STRIDE + 8] = __float2half_rn(wk[8]);
            }
        }
        sr[r * SR_PITCH + cc] = val;
    }
    __syncthreads();

    // Phase 3: w_mod for pixel rows [h0-1,h0+17), cols [w0-1,w0+33):
    // argmin/argmax over the img_r window, then ONE dynamic LDS u16 read of
    // the cached weight (never a dynamically-indexed register array — R5).
    for (int idx = t; idx < WM_ROWS * WM_COLS; idx += 256) {
        int r = idx / WM_COLS, cc = idx - r * WM_COLS;
        int h = h0 - 1 + r, w = w0 - 1 + cc;
        float wmv = 0.f;
        if (h >= 0 && h < HH && w >= 0 && w < WD) {
            float rv[9];
#pragma unroll
            for (int k = 0; k < 9; ++k)
                rv[k] = sr[(r + k / 3) * SR_PITCH + cc + k % 3];
            int amin = 0, amax = 0;
            float vmin = rv[0], vmax = rv[0];
#pragma unroll
            for (int k = 1; k < 9; ++k) {
                if (rv[k] < vmin) { vmin = rv[k]; amin = k; }  // first occurrence
                if (rv[k] > vmax) { vmax = rv[k]; amax = k; }
            }
            int ksel = dil ? amax : amin;
            wmv = __half2float(w9[idx * W9_STRIDE + ksel]);
        }
        swm[r * WM_PITCH + cc] = wmv;
    }
    __syncthreads();

    // Phase 4: final weighted average per output pixel, 3 channels at once.
#pragma unroll
    for (int rr = 0; rr < (TH * TW) / 256; ++rr) {
        int idx = rr * 256 + t;
        int ly = idx / TW, lx = idx - ly * TW;
        float wk[9], den = 0.f;
#pragma unroll
        for (int k = 0; k < 9; ++k) {
            wk[k] = swm[(ly + k / 3) * WM_PITCH + lx + k % 3];
            den += wk[k];
        }
        float rden = 1.f / den;
        v2f nxy = {0.f, 0.f};
        float nz2 = 0.f;
#pragma unroll
        for (int k = 0; k < 9; ++k) {
            float4 tp = sp4[(ly + 2 + k / 3) * SP_COLS + lx + 2 + k % 3];
            v2f pxy = {tp.x, tp.y};
            nxy += pxy * wk[k];   // v_pk_fma_f32
            nz2 += tp.z * wk[k];
        }
        size_t o = ((size_t)b * CN * HH + h0 + ly) * WD + w0 + lx;
        out[o] = ((int)(nxy.x * rden)) & 255;
        out[o + (size_t)HH * WD] = ((int)(nxy.y * rden)) & 255;
        out[o + 2 * (size_t)HH * WD] = ((int)(nz2 * rden)) & 255;
    }
}

extern "C" void kernel_launch(void* const* d_in, const int* in_sizes, int n_in,
                              void* d_out, int out_size, void* d_ws, size_t ws_size,
                              hipStream_t stream) {
    const float* img   = (const float*)d_in[0];
    const float* noise = (const float*)d_in[1];
    const int* ids_sel = (const int*)d_in[2];
    const int* ids_dil = (const int*)d_in[3];
    int* out = (int*)d_out;

    dim3 grid(WD / TW, HH / TH, BN);  // 16 x 32 x 8 = 4096 blocks
    fused<<<grid, 256, 0, stream>>>(img, noise, ids_sel, ids_dil, out);
}